// Round 11
// baseline (2762.258 us; speedup 1.0000x reference)
//
#include <hip/hip_runtime.h>
#include <math.h>

#define B_   256
#define N_   1536
#define OBS_ 20
#define HOR_ 30

typedef __bf16 bf16;
typedef bf16  bf16x8 __attribute__((ext_vector_type(8)));
typedef float f32x4  __attribute__((ext_vector_type(4)));

// ---------------------------------------------------------------------------
// Device fp32 GEMM, 32x64 tile, 256 threads, register-prefetch double buffer.
// ---------------------------------------------------------------------------
__device__ __forceinline__ void dev_gemm(
    const float* __restrict__ A, int lda,
    const float* __restrict__ Bw, int ldb,
    float* __restrict__ C, bf16* __restrict__ Cb, int ldc,
    int K, const float* __restrict__ colBias,
    int by, int bx, float* smem)
{
    float (*As)[36] = (float(*)[36])smem;
    float (*Bs)[68] = (float(*)[68])(smem + 16 * 36);
    const int tid = threadIdx.x;
    const int n0 = by * 32, j0 = bx * 64;
    const int a_k = tid & 15, a_r = tid >> 4;
    const int b_j = tid & 63, b_k = tid >> 6;
    const int tx = tid & 15, ty = tid >> 4;
    float acc[2][4] = {};
    float pa0 = A[(size_t)(n0 + a_r) * lda + a_k];
    float pa1 = A[(size_t)(n0 + a_r + 16) * lda + a_k];
    float pb[4];
#pragma unroll
    for (int i = 0; i < 4; i++) pb[i] = Bw[(size_t)(b_k + 4 * i) * ldb + j0 + b_j];
    for (int k0 = 0; k0 < K; k0 += 16) {
        As[a_k][a_r] = pa0;
        As[a_k][a_r + 16] = pa1;
#pragma unroll
        for (int i = 0; i < 4; i++) Bs[b_k + 4 * i][b_j] = pb[i];
        __syncthreads();
        if (k0 + 16 < K) {
            pa0 = A[(size_t)(n0 + a_r) * lda + k0 + 16 + a_k];
            pa1 = A[(size_t)(n0 + a_r + 16) * lda + k0 + 16 + a_k];
#pragma unroll
            for (int i = 0; i < 4; i++)
                pb[i] = Bw[(size_t)(k0 + 16 + b_k + 4 * i) * ldb + j0 + b_j];
        }
#pragma unroll
        for (int kk = 0; kk < 16; kk++) {
            float a0 = As[kk][ty * 2];
            float a1 = As[kk][ty * 2 + 1];
            float4 bv = *(const float4*)&Bs[kk][tx * 4];
            float bb[4] = {bv.x, bv.y, bv.z, bv.w};
#pragma unroll
            for (int j = 0; j < 4; j++) { acc[0][j] += a0 * bb[j]; acc[1][j] += a1 * bb[j]; }
        }
        __syncthreads();
    }
#pragma unroll
    for (int i = 0; i < 2; i++) {
        int n = n0 + ty * 2 + i;
#pragma unroll
        for (int j = 0; j < 4; j++) {
            int jj = j0 + tx * 4 + j;
            float v = acc[i][j];
            if (colBias) v += colBias[jj];
            if (C)  C[(size_t)n * ldc + jj] = v;
            if (Cb) Cb[(size_t)n * ldc + jj] = (bf16)v;
        }
    }
}

// ---------------------------------------------------------------------------
__device__ __forceinline__ void dev_pack(
    int bi, const float* __restrict__ srcF, const bf16* __restrict__ srcB,
    int srcRows, int KC, int J, int lds, bf16* __restrict__ dst)
{
    int idx = bi * 256 + threadIdx.x;
    int total = (J / 16) * KC * 64;
    if (idx >= total) return;
    int lane = idx & 63;
    int kc = (idx >> 6) % KC;
    int jg = idx / (64 * KC);
    int k0 = kc * 32 + (lane >> 4) * 8;
    int col = jg * 16 + (lane & 15);
    bf16x8 v;
#pragma unroll
    for (int i = 0; i < 8; i++) {
        int r = k0 + i;
        float x = 0.f;
        if (r < srcRows) x = srcF ? srcF[(size_t)r * lds + col] : (float)srcB[(size_t)r * lds + col];
        v[i] = (bf16)x;
    }
    *(bf16x8*)&dst[(size_t)idx * 8] = v;
}

__device__ __forceinline__ void dev_emb_obs(
    int bi, const float* __restrict__ obs, const float* __restrict__ Wemb,
    const float* __restrict__ bemb, float* __restrict__ emb_obs)
{
    int tid = bi * 256 + threadIdx.x;
    if (tid >= OBS_ * B_ * 32) return;
    int r = tid >> 5, e = tid & 31;
    float v = obs[r * 2] * Wemb[e] + obs[r * 2 + 1] * Wemb[32 + e] + bemb[e];
    emb_obs[tid] = fmaxf(v, 0.f);
}

// weff: float4 inner loop (4x fewer L2 requests; d-ascending inside the
// vector keeps the fp32 accumulation chain bit-identical).
__device__ __forceinline__ void dev_weff(
    int r, const float* __restrict__ Wqkv, const float* __restrict__ bqkv,
    float* __restrict__ Weff, float* smem)
{
    float* qrow = smem;
    const int t = threadIdx.x;
    for (int j = t; j < 512; j += 256)
        qrow[j] = (r < 512) ? Wqkv[(size_t)r * 1536 + j] : bqkv[j];
    __syncthreads();
    const int h = t >> 5, c = t & 31;
    const float* kp = &Wqkv[(size_t)c * 1536 + 512 + h * 64];
    const float* qp = &qrow[h * 64];
    float acc = 0.f;
#pragma unroll
    for (int d4 = 0; d4 < 16; d4++) {
        float4 kv = *(const float4*)&kp[d4 * 4];
        float4 qv = *(const float4*)&qp[d4 * 4];
        acc += qv.x * kv.x; acc += qv.y * kv.y;
        acc += qv.z * kv.z; acc += qv.w * kv.w;
    }
    Weff[(size_t)r * 256 + t] = acc;
}

__device__ __forceinline__ void dev_wov(
    int row, const float* __restrict__ Wqkv, const float* __restrict__ Wo,
    bf16* __restrict__ WovCat, float* smem)
{
    float* vrow = smem;
    const int h = row >> 5, c = row & 31;
    const int t = threadIdx.x;
    if (t < 64) vrow[t] = Wqkv[(size_t)c * 1536 + 1024 + h * 64 + t];
    __syncthreads();
    for (int j = t; j < 512; j += 256) {
        float acc = 0.f;
#pragma unroll 8
        for (int d = 0; d < 64; d++)
            acc += vrow[d] * Wo[(size_t)(h * 64 + d) * 512 + j];
        WovCat[(size_t)row * 512 + j] = (bf16)acc;
    }
}

// ---------------------------------------------------------------------------
// Prologue phase 1: all independent work, one launch, 2688 blocks.
// ---------------------------------------------------------------------------
__global__ __launch_bounds__(256) void prologue1_k(
    const float* __restrict__ obs, const float* __restrict__ Wemb,
    const float* __restrict__ bemb, float* __restrict__ emb_obs,
    const float* __restrict__ Wqkv, const float* __restrict__ bqkv,
    float* __restrict__ Weff,
    const float* __restrict__ Wo, bf16* __restrict__ WovCat,
    const float* __restrict__ feat, float* __restrict__ featv,
    const float* __restrict__ Wfus, const float* __restrict__ bfus,
    float* __restrict__ feat_fus,
    const float* __restrict__ Wff1, bf16* __restrict__ BpF1,
    const float* __restrict__ Wff2, bf16* __restrict__ BpF2,
    bf16* __restrict__ BpFus)
{
    __shared__ __attribute__((aligned(16))) float smem[16 * 36 + 16 * 68];
    const int b = blockIdx.x;
    if (b < 640) {
        dev_emb_obs(b, obs, Wemb, bemb, emb_obs);
    } else if (b < 1153) {
        dev_weff(b - 640, Wqkv, bqkv, Weff, smem);
    } else if (b < 1409) {
        dev_wov(b - 1153, Wqkv, Wo, WovCat, smem);
    } else if (b < 1473) {            // featv = feat @ Wv + b_qkv[1024:]
        int i = b - 1409;
        dev_gemm(feat, 448, Wqkv + 64 * 1536 + 1024, 1536,
                 featv, nullptr, 512, 448, bqkv + 1024, i >> 3, i & 7, smem);
    } else if (b < 1489) {            // WovCat rows 256..319
        int i = b - 1473;
        dev_gemm(Wqkv + 32 * 1536 + 1024, 1536, Wo, 512,
                 nullptr, WovCat + 256 * 512, 512, 512, nullptr, i >> 3, i & 7, smem);
    } else if (b < 1545) {            // feat_fus = feat @ W_fus[519:] + b_fus
        int i = b - 1489;
        dev_gemm(feat, 448, Wfus + 519 * 448, 448,
                 feat_fus, nullptr, 448, 448, bfus, i / 7, i % 7, smem);
    } else if (b < 2057) {
        dev_pack(b - 1545, Wff1, nullptr, 512, 16, 2048, 2048, BpF1);
    } else if (b < 2569) {
        dev_pack(b - 2057, Wff2, nullptr, 2048, 64, 512, 512, BpF2);
    } else {
        dev_pack(b - 2569, Wfus, nullptr, 519, 17, 448, 448, BpFus);
    }
}

// ---------------------------------------------------------------------------
// Prologue phase 2: depends on phase 1. 168 blocks.
// ---------------------------------------------------------------------------
__global__ __launch_bounds__(256) void prologue2_k(
    const float* __restrict__ feat, const float* __restrict__ Weff,
    float* __restrict__ featqp,
    const float* __restrict__ featv, const float* __restrict__ Wo,
    const float* __restrict__ b_o, float* __restrict__ featvO,
    const bf16* __restrict__ WovCat, bf16* __restrict__ BpA)
{
    __shared__ __attribute__((aligned(16))) float smem[16 * 36 + 16 * 68];
    const int b = blockIdx.x;
    if (b < 32) {                     // featqp = feat @ Weff[64:] + Weff[512]
        int i = b;
        dev_gemm(feat, 448, Weff + 64 * 256, 256,
                 featqp, nullptr, 256, 448, Weff + 512 * 256, i >> 2, i & 3, smem);
    } else if (b < 96) {              // featvO = featv @ W_o + b_o
        int i = b - 32;
        dev_gemm(featv, 512, Wo, 512,
                 featvO, nullptr, 512, 512, b_o, i >> 3, i & 7, smem);
    } else {
        dev_pack(b - 96, nullptr, WovCat, 288, 9, 512, 512, BpA);
    }
}

// ---------------------------------------------------------------------------
// 64-row MFMA GEMM, generalized (float C / bf16 Cb / colBias / rowMat / relu).
// B-fragments loaded once per 2 row-tiles -> B L2 traffic halved vs 32-row.
// grid (J/64, rows/64), block 256. Per-output K-chain identical to fgemm_k.
// ---------------------------------------------------------------------------
template<int KC>
__global__ __launch_bounds__(256) void fgemm64_k(
    const bf16* __restrict__ A, int lda,
    const bf16* __restrict__ Bp,
    float* __restrict__ C, bf16* __restrict__ Cb, int ldc,
    const float* __restrict__ colBias,
    const float* __restrict__ rowMat, int ldRm,
    int doRelu)
{
    const int n0 = blockIdx.y * 64;
    const int j0g = blockIdx.x * 4;
    const int tid = threadIdx.x;
    const int w = tid >> 6, lane = tid & 63;
    const int quad = lane >> 4, m15 = lane & 15;
    const int r0 = (w & 1) * 16;
    const int cg = (w >> 1) * 2;
    const bf16* Ar0 = &A[(size_t)(n0 + r0 + m15) * lda + quad * 8];
    const bf16* Ar1 = &A[(size_t)(n0 + 32 + r0 + m15) * lda + quad * 8];
    const bf16* B0 = &Bp[((size_t)(j0g + cg) * KC * 64 + lane) * 8];
    const bf16* B1 = &Bp[((size_t)(j0g + cg + 1) * KC * 64 + lane) * 8];
    f32x4 acc00 = {}, acc01 = {}, acc10 = {}, acc11 = {};
#pragma unroll 8
    for (int kc = 0; kc < KC; kc++) {
        bf16x8 a0 = *(const bf16x8*)&Ar0[kc * 32];
        bf16x8 a1 = *(const bf16x8*)&Ar1[kc * 32];
        bf16x8 b0 = *(const bf16x8*)&B0[(size_t)kc * 512];
        bf16x8 b1 = *(const bf16x8*)&B1[(size_t)kc * 512];
        acc00 = __builtin_amdgcn_mfma_f32_16x16x32_bf16(a0, b0, acc00, 0, 0, 0);
        acc01 = __builtin_amdgcn_mfma_f32_16x16x32_bf16(a0, b1, acc01, 0, 0, 0);
        acc10 = __builtin_amdgcn_mfma_f32_16x16x32_bf16(a1, b0, acc10, 0, 0, 0);
        acc11 = __builtin_amdgcn_mfma_f32_16x16x32_bf16(a1, b1, acc11, 0, 0, 0);
    }
#pragma unroll
    for (int rt = 0; rt < 2; rt++) {
#pragma unroll
        for (int g = 0; g < 2; g++) {
            f32x4 a = rt ? (g ? acc11 : acc10) : (g ? acc01 : acc00);
            int j = (j0g + cg + g) * 16 + m15;
            float cb = colBias ? colBias[j] : 0.f;
#pragma unroll
            for (int r = 0; r < 4; r++) {
                int n = n0 + rt * 32 + r0 + quad * 4 + r;
                float v = a[r] + cb;
                if (rowMat) v += rowMat[(size_t)(n / 6) * ldRm + j];
                if (doRelu) v = fmaxf(v, 0.f);
                if (C)  C[(size_t)n * ldc + j] = v;
                if (Cb) Cb[(size_t)n * ldc + j] = (bf16)v;
            }
        }
    }
}

// ---------------------------------------------------------------------------
// 64-row MFMA GEMM (FF1 specialization: bf16 out + relu + colBias).
// ---------------------------------------------------------------------------
template<int KC>
__global__ __launch_bounds__(256) void fgemm64r_k(
    const bf16* __restrict__ A, int lda,
    const bf16* __restrict__ Bp,
    bf16* __restrict__ Cb, int ldc,
    const float* __restrict__ colBias)
{
    const int n0 = blockIdx.y * 64;
    const int j0g = blockIdx.x * 4;
    const int tid = threadIdx.x;
    const int w = tid >> 6, lane = tid & 63;
    const int quad = lane >> 4, m15 = lane & 15;
    const int r0 = (w & 1) * 16;
    const int cg = (w >> 1) * 2;
    const bf16* Ar0 = &A[(size_t)(n0 + r0 + m15) * lda + quad * 8];
    const bf16* Ar1 = &A[(size_t)(n0 + 32 + r0 + m15) * lda + quad * 8];
    const bf16* B0 = &Bp[((size_t)(j0g + cg) * KC * 64 + lane) * 8];
    const bf16* B1 = &Bp[((size_t)(j0g + cg + 1) * KC * 64 + lane) * 8];
    f32x4 acc00 = {}, acc01 = {}, acc10 = {}, acc11 = {};
#pragma unroll 8
    for (int kc = 0; kc < KC; kc++) {
        bf16x8 a0 = *(const bf16x8*)&Ar0[kc * 32];
        bf16x8 a1 = *(const bf16x8*)&Ar1[kc * 32];
        bf16x8 b0 = *(const bf16x8*)&B0[(size_t)kc * 512];
        bf16x8 b1 = *(const bf16x8*)&B1[(size_t)kc * 512];
        acc00 = __builtin_amdgcn_mfma_f32_16x16x32_bf16(a0, b0, acc00, 0, 0, 0);
        acc01 = __builtin_amdgcn_mfma_f32_16x16x32_bf16(a0, b1, acc01, 0, 0, 0);
        acc10 = __builtin_amdgcn_mfma_f32_16x16x32_bf16(a1, b0, acc10, 0, 0, 0);
        acc11 = __builtin_amdgcn_mfma_f32_16x16x32_bf16(a1, b1, acc11, 0, 0, 0);
    }
#pragma unroll
    for (int rt = 0; rt < 2; rt++) {
#pragma unroll
        for (int g = 0; g < 2; g++) {
            f32x4 a = rt ? (g ? acc11 : acc10) : (g ? acc01 : acc00);
            int j = (j0g + cg + g) * 16 + m15;
            float cb = colBias[j];
#pragma unroll
            for (int r = 0; r < 4; r++) {
                int n = n0 + rt * 32 + r0 + quad * 4 + r;
                float v = fmaxf(a[r] + cb, 0.f);
                Cb[(size_t)n * ldc + j] = (bf16)v;
            }
        }
    }
}

// ---------------------------------------------------------------------------
// MERGED attn2: finish-work of step s-1 (out, dout, next-state, qp in LDS)
// then attention for step s. grid N x 256. At s==0, qp comes from init_k.
// ---------------------------------------------------------------------------
__global__ __launch_bounds__(256) void attn2_k(
    const float* __restrict__ qp_g,      // init qp (used when s==0)
    const float* __restrict__ emb_obs,
    float* __restrict__ emb_gen,
    const float* __restrict__ fusv,
    const float* __restrict__ Wout, const float* __restrict__ bout,
    const float* __restrict__ Wemb, const float* __restrict__ bemb,
    const float* __restrict__ loc,
    const float* __restrict__ Weff, const float* __restrict__ featqp,
    float* __restrict__ dout,
    float* __restrict__ A1f, bf16* __restrict__ ecA1b,
    float* __restrict__ small5, int s)
{
    __shared__ float qp_s[256];
    __shared__ float emb_s[50 * 33];
    __shared__ float at8[8][64];
    __shared__ float red[8];
    __shared__ float osh[2];
    __shared__ float A1s[64];
    const int n = blockIdx.x, b = n / 6, m = n % 6, tid = threadIdx.x;
    const int tlen = OBS_ + s;

    if (s == 0) {
        qp_s[tid] = qp_g[(size_t)n * 256 + tid];
    } else {
        // ---- finish-work of step s-1 (identical reduction order) ----
        float f0 = fusv[(size_t)n * 448 + tid];
        float p0 = f0 * Wout[tid * 2];
        float p1 = f0 * Wout[tid * 2 + 1];
        if (tid < 192) {
            float f1 = fusv[(size_t)n * 448 + 256 + tid];
            p0 += f1 * Wout[(256 + tid) * 2];
            p1 += f1 * Wout[(256 + tid) * 2 + 1];
        }
#pragma unroll
        for (int o = 32; o > 0; o >>= 1) { p0 += __shfl_xor(p0, o, 64); p1 += __shfl_xor(p1, o, 64); }
        int w = tid >> 6, lane = tid & 63;
        if (lane == 0) { red[w] = p0; red[4 + w] = p1; }
        __syncthreads();
        if (tid == 0) {
            float o0 = red[0] + red[1] + red[2] + red[3] + bout[0];
            float o1 = red[4] + red[5] + red[6] + red[7] + bout[1];
            osh[0] = o0; osh[1] = o1;
            dout[(size_t)b * 360 + m * 60 + (s - 1) * 2]     = o0;
            dout[(size_t)b * 360 + m * 60 + (s - 1) * 2 + 1] = o1;
        }
        __syncthreads();
        float o0 = osh[0], o1 = osh[1];
        float g0 = loc[b * 12 + m * 2], g1 = loc[b * 12 + m * 2 + 1];
        float d0 = g0 - o0, d1 = g1 - o1;
        float tc = (float)(OBS_ + s);    // (s-1)+1 frame index
        if (tid < 32) {
            float e = fmaxf(o0 * Wemb[tid] + o1 * Wemb[32 + tid] + bemb[tid], 0.f);
            emb_gen[((size_t)(s - 1) * N_ + n) * 32 + tid] = e;
            A1s[tid] = e;
        } else if (tid < 64) {
            int c = tid - 32;
            float v;
            if      (c < 8)  v = (c & 1) ? g1 : g0;
            else if (c < 16) v = (c & 1) ? o1 : o0;
            else if (c < 24) v = (c & 1) ? d1 : d0;
            else             v = tc;
            A1s[tid] = v;
        }
        if (tid < 7) {
            float v2 = (tid==0)?o0:(tid==1)?o1:(tid==2)?g0:(tid==3)?g1:(tid==4)?d0:(tid==5)?d1:tc;
            small5[n * 8 + tid] = v2;
        }
        __syncthreads();
        if (tid < 64) {
            A1f[(size_t)n * 64 + tid] = A1s[tid];
            if (tid >= 32) ecA1b[(size_t)n * 288 + 256 + (tid - 32)] = (bf16)A1s[tid];
        }
        float acc = featqp[(size_t)b * 256 + tid];
#pragma unroll 8
        for (int k = 0; k < 64; k++) acc += A1s[k] * Weff[k * 256 + tid];
        qp_s[tid] = acc;
    }

    // ---- stage emb history; newest generated row comes from A1s ----
    for (int idx = tid; idx < tlen * 32; idx += 256) {
        int l = idx >> 5, c = idx & 31;
        float v;
        if (l < OBS_)                 v = emb_obs[((size_t)l * B_ + b) * 32 + c];
        else if (l == tlen - 1)       v = A1s[c];     // only reached when s>=1
        else                          v = emb_gen[((size_t)(l - OBS_) * N_ + n) * 32 + c];
        emb_s[l * 33 + c] = v;
    }
    __syncthreads();

    // ---- attention scores + softmax (per-wave, 2 heads each) ----
    const int w = tid >> 6, lane = tid & 63;
#pragma unroll
    for (int hh = 0; hh < 2; hh++) {
        const int h = w * 2 + hh;
        float sc = -1e30f;
        if (lane < tlen) {
            float s_ = 0.f;
#pragma unroll 8
            for (int c = 0; c < 32; c++) s_ += emb_s[lane * 33 + c] * qp_s[h * 32 + c];
            sc = s_ * 0.125f;
        }
        float mx = sc;
#pragma unroll
        for (int o = 32; o > 0; o >>= 1) mx = fmaxf(mx, __shfl_xor(mx, o, 64));
        float e = (lane < tlen) ? __expf(sc - mx) : 0.f;
        float sm = e;
#pragma unroll
        for (int o = 32; o > 0; o >>= 1) sm += __shfl_xor(sm, o, 64);
        at8[h][lane] = e / sm;
    }
    __syncthreads();

    // ---- context: 1 thread per (head, col); l-ascending = bit-identical ----
    {
        const int h = tid >> 5, c = tid & 31;
        float ec = 0.f;
        for (int l = 0; l < tlen; l++) ec += at8[h][l] * emb_s[l * 33 + c];
        ecA1b[(size_t)n * 288 + h * 32 + c] = (bf16)ec;
    }
}

// ---------------------------------------------------------------------------
// LN1: h1 = LN([A1f|feat] + a) -> h1f fp32 + h1b bf16. grid N x 256.
// ---------------------------------------------------------------------------
__global__ __launch_bounds__(256) void ln1_k(
    const float* __restrict__ a, const float* __restrict__ A1f,
    const float* __restrict__ feat, const float* __restrict__ g,
    const float* __restrict__ bt, float* __restrict__ h1f, bf16* __restrict__ h1b)
{
    __shared__ float red[8];
    const int n = blockIdx.x, b = n / 6, tid = threadIdx.x;
    float r[2]; float s = 0.f, sq = 0.f;
#pragma unroll
    for (int i = 0; i < 2; i++) {
        int j = tid + i * 256;
        float x = (j < 64) ? A1f[(size_t)n * 64 + j] : feat[(size_t)b * 448 + (j - 64)];
        float v = a[(size_t)n * 512 + j] + x;
        r[i] = v; s += v; sq += v * v;
    }
#pragma unroll
    for (int o = 32; o > 0; o >>= 1) { s += __shfl_xor(s, o, 64); sq += __shfl_xor(sq, o, 64); }
    int w = tid >> 6, lane = tid & 63;
    if (lane == 0) { red[w] = s; red[4 + w] = sq; }
    __syncthreads();
    s  = red[0] + red[1] + red[2] + red[3];
    sq = red[4] + red[5] + red[6] + red[7];
    float mu = s * (1.f / 512.f);
    float var = sq * (1.f / 512.f) - mu * mu;
    float rs = rsqrtf(var + 1e-5f);
#pragma unroll
    for (int i = 0; i < 2; i++) {
        int j = tid + i * 256;
        float v = (r[i] - mu) * rs * g[j] + bt[j];
        h1f[(size_t)n * 512 + j] = v;
        h1b[(size_t)n * 512 + j] = (bf16)v;
    }
}

// ---------------------------------------------------------------------------
// LN2: h2p = [LN(h1+ff) | small5 | zeros] as bf16, ld 544. grid N x 256.
// ---------------------------------------------------------------------------
__global__ __launch_bounds__(256) void ln2_k(
    const float* __restrict__ h1, const float* __restrict__ ff,
    const float* __restrict__ g, const float* __restrict__ bt,
    const float* __restrict__ small5, bf16* __restrict__ h2p)
{
    __shared__ float red[8];
    const int n = blockIdx.x, tid = threadIdx.x;
    float r[2]; float s = 0.f, sq = 0.f;
#pragma unroll
    for (int i = 0; i < 2; i++) {
        int j = tid + i * 256;
        float v = h1[(size_t)n * 512 + j] + ff[(size_t)n * 512 + j];
        r[i] = v; s += v; sq += v * v;
    }
#pragma unroll
    for (int o = 32; o > 0; o >>= 1) { s += __shfl_xor(s, o, 64); sq += __shfl_xor(sq, o, 64); }
    int w = tid >> 6, lane = tid & 63;
    if (lane == 0) { red[w] = s; red[4 + w] = sq; }
    __syncthreads();
    s  = red[0] + red[1] + red[2] + red[3];
    sq = red[4] + red[5] + red[6] + red[7];
    float mu = s * (1.f / 512.f);
    float var = sq * (1.f / 512.f) - mu * mu;
    float rs = rsqrtf(var + 1e-5f);
#pragma unroll
    for (int i = 0; i < 2; i++) {
        int j = tid + i * 256;
        h2p[(size_t)n * 544 + j] = (bf16)((r[i] - mu) * rs * g[j] + bt[j]);
    }
    if (tid < 7)  h2p[(size_t)n * 544 + 512 + tid] = (bf16)small5[n * 8 + tid];
    if (tid < 25) h2p[(size_t)n * 544 + 519 + tid] = (bf16)0.f;
}

// ---------------------------------------------------------------------------
// Next-state producer (shared logic)
// ---------------------------------------------------------------------------
__device__ __forceinline__ void next_state(
    int n, int b, int t, float o0, float o1, float g0, float g1, float tc,
    const float* Wemb, const float* bemb, const float* Weff, const float* featqp,
    float* emb_dst, float* A1f, bf16* ecA1b, float* small5, float* qp, float* A1s)
{
    float d0 = g0 - o0, d1 = g1 - o1;
    if (t < 32) {
        float e = fmaxf(o0 * Wemb[t] + o1 * Wemb[32 + t] + bemb[t], 0.f);
        if (emb_dst) emb_dst[t] = e;
        A1s[t] = e;
    } else if (t < 64) {
        int c = t - 32;
        float v;
        if      (c < 8)  v = (c & 1) ? g1 : g0;
        else if (c < 16) v = (c & 1) ? o1 : o0;
        else if (c < 24) v = (c & 1) ? d1 : d0;
        else             v = tc;
        A1s[t] = v;
    }
    if (t < 7) {
        float v2 = (t==0)?o0:(t==1)?o1:(t==2)?g0:(t==3)?g1:(t==4)?d0:(t==5)?d1:tc;
        small5[n * 8 + t] = v2;
    }
    __syncthreads();
    if (t < 64) {
        A1f[(size_t)n * 64 + t] = A1s[t];
        if (t >= 32) ecA1b[(size_t)n * 288 + 256 + (t - 32)] = (bf16)A1s[t];
    }
    float acc = featqp[(size_t)b * 256 + t];
#pragma unroll 8
    for (int k = 0; k < 64; k++) acc += A1s[k] * Weff[k * 256 + t];
    qp[(size_t)n * 256 + t] = acc;
}

__global__ __launch_bounds__(256) void init_k(
    const float* __restrict__ obs, const float* __restrict__ emb_obs,
    const float* __restrict__ loc, const float* __restrict__ Weff,
    const float* __restrict__ featqp,
    float* __restrict__ A1f, bf16* __restrict__ ecA1b,
    float* __restrict__ small5, float* __restrict__ qp)
{
    __shared__ float A1s[64];
    const int n = blockIdx.x, b = n / 6, m = n % 6, t = threadIdx.x;
    float o0 = obs[(19 * B_ + b) * 2], o1 = obs[(19 * B_ + b) * 2 + 1];
    float g0 = loc[b * 12 + m * 2], g1 = loc[b * 12 + m * 2 + 1];
    if (t < 32) {
        A1s[t] = emb_obs[((size_t)19 * B_ + b) * 32 + t];
    } else if (t < 64) {
        int c = t - 32; float d0 = g0 - o0, d1 = g1 - o1; float tc = 20.f;
        float v;
        if      (c < 8)  v = (c & 1) ? g1 : g0;
        else if (c < 16) v = (c & 1) ? o1 : o0;
        else if (c < 24) v = (c & 1) ? d1 : d0;
        else             v = tc;
        A1s[t] = v;
    }
    if (t < 7) {
        float d0 = g0 - o0, d1 = g1 - o1; float tc = 20.f;
        float v2 = (t==0)?o0:(t==1)?o1:(t==2)?g0:(t==3)?g1:(t==4)?d0:(t==5)?d1:tc;
        small5[n * 8 + t] = v2;
    }
    __syncthreads();
    if (t < 64) {
        A1f[(size_t)n * 64 + t] = A1s[t];
        if (t >= 32) ecA1b[(size_t)n * 288 + 256 + (t - 32)] = (bf16)A1s[t];
    }
    float acc = featqp[(size_t)b * 256 + t];
#pragma unroll 8
    for (int k = 0; k < 64; k++) acc += A1s[k] * Weff[k * 256 + t];
    qp[(size_t)n * 256 + t] = acc;
}

// ---------------------------------------------------------------------------
// finish: trailing step only (writes dout for s=29).
// ---------------------------------------------------------------------------
__global__ __launch_bounds__(256) void finish_k(
    const float* __restrict__ fusv, const float* __restrict__ Wout,
    const float* __restrict__ bout, const float* __restrict__ Wemb,
    const float* __restrict__ bemb, const float* __restrict__ loc,
    const float* __restrict__ Weff, const float* __restrict__ featqp,
    float* __restrict__ dout, float* __restrict__ emb_gen,
    float* __restrict__ A1f, bf16* __restrict__ ecA1b,
    float* __restrict__ small5, float* __restrict__ qp, int s)
{
    __shared__ float red[8];
    __shared__ float osh[2];
    __shared__ float A1s[64];
    const int n = blockIdx.x, b = n / 6, m = n % 6, t = threadIdx.x;
    float f0 = fusv[(size_t)n * 448 + t];
    float p0 = f0 * Wout[t * 2];
    float p1 = f0 * Wout[t * 2 + 1];
    if (t < 192) {
        float f1 = fusv[(size_t)n * 448 + 256 + t];
        p0 += f1 * Wout[(256 + t) * 2];
        p1 += f1 * Wout[(256 + t) * 2 + 1];
    }
#pragma unroll
    for (int o = 32; o > 0; o >>= 1) { p0 += __shfl_xor(p0, o, 64); p1 += __shfl_xor(p1, o, 64); }
    int w = t >> 6, lane = t & 63;
    if (lane == 0) { red[w] = p0; red[4 + w] = p1; }
    __syncthreads();
    if (t == 0) {
        float o0 = red[0] + red[1] + red[2] + red[3] + bout[0];
        float o1 = red[4] + red[5] + red[6] + red[7] + bout[1];
        osh[0] = o0; osh[1] = o1;
        dout[(size_t)b * 360 + m * 60 + s * 2]     = o0;
        dout[(size_t)b * 360 + m * 60 + s * 2 + 1] = o1;
    }
    __syncthreads();
    float o0 = osh[0], o1 = osh[1];
    float g0 = loc[b * 12 + m * 2], g1 = loc[b * 12 + m * 2 + 1];
    next_state(n, b, t, o0, o1, g0, g1, (float)(OBS_ + s + 1),
               Wemb, bemb, Weff, featqp,
               &emb_gen[((size_t)s * N_ + n) * 32], A1f, ecA1b, small5, qp, A1s);
}

// ---------------------------------------------------------------------------
extern "C" void kernel_launch(void* const* d_in, const int* in_sizes, int n_in,
                              void* d_out_, int out_size, void* d_ws, size_t ws_size,
                              hipStream_t stream) {
    (void)in_sizes; (void)n_in; (void)out_size; (void)ws_size;
    const float* feat  = (const float*)d_in[0];
    const float* loc   = (const float*)d_in[1];
    const float* obs   = (const float*)d_in[2];
    const float* W_emb = (const float*)d_in[3];
    const float* b_emb = (const float*)d_in[4];
    const float* W_qkv = (const float*)d_in[5];
    const float* b_qkv = (const float*)d_in[6];
    const float* W_o   = (const float*)d_in[7];
    const float* b_o   = (const float*)d_in[8];
    const float* W_ff1 = (const float*)d_in[9];
    const float* b_ff1 = (const float*)d_in[10];
    const float* W_ff2 = (const float*)d_in[11];
    const float* b_ff2 = (const float*)d_in[12];
    const float* ln1_g = (const float*)d_in[13];
    const float* ln1_b = (const float*)d_in[14];
    const float* ln2_g = (const float*)d_in[15];
    const float* ln2_b = (const float*)d_in[16];
    const float* W_fus = (const float*)d_in[17];
    const float* b_fus = (const float*)d_in[18];
    const float* W_out = (const float*)d_in[19];
    const float* b_out = (const float*)d_in[20];
    float* dout = (float*)d_out_;

    float* ws = (float*)d_ws;
    float* Weff     = ws; ws += 513 * 256;
    float* featqp   = ws; ws += 256 * 256;
    float* featv    = ws; ws += 256 * 512;
    float* featvO   = ws; ws += 256 * 512;
    float* feat_fus = ws; ws += 256 * 448;
    float* emb_obs  = ws; ws += OBS_ * B_ * 32;
    float* emb_gen  = ws; ws += HOR_ * N_ * 32;
    float* qp       = ws; ws += (size_t)N_ * 256;
    float* A1f      = ws; ws += (size_t)N_ * 64;
    float* small5   = ws; ws += (size_t)N_ * 8;
    float* h1f      = ws; ws += (size_t)N_ * 512;
    float* aF       = ws; ws += (size_t)N_ * 512;
    float* ffB      = ws; ws += (size_t)N_ * 512;
    float* fusv     = ws; ws += (size_t)N_ * 448;
    bf16* WovCat = (bf16*)ws; ws += (320 * 512) / 2;
    bf16* BpA    = (bf16*)ws; ws += (32 * 9 * 512) / 2;     // 512 cols, KC=9
    bf16* BpF1   = (bf16*)ws; ws += (128 * 16 * 512) / 2;   // 2048 cols, KC=16
    bf16* BpF2   = (bf16*)ws; ws += (32 * 64 * 512) / 2;    // 512 cols, KC=64
    bf16* BpFus  = (bf16*)ws; ws += (28 * 17 * 512) / 2;    // 448 cols, KC=17
    bf16* ecA1b  = (bf16*)ws; ws += ((size_t)N_ * 288) / 2;
    bf16* h1b    = (bf16*)ws; ws += ((size_t)N_ * 512) / 2;
    bf16* f1b    = (bf16*)ws; ws += ((size_t)N_ * 2048) / 2;
    bf16* h2p    = (bf16*)ws; ws += ((size_t)N_ * 544) / 2;

    // ---- prologue: 3 launches ----
    prologue1_k<<<dim3(2688), dim3(256), 0, stream>>>(
        obs, W_emb, b_emb, emb_obs, W_qkv, b_qkv, Weff, W_o, WovCat,
        feat, featv, W_fus, b_fus, feat_fus, W_ff1, BpF1, W_ff2, BpF2, BpFus);
    prologue2_k<<<dim3(168), dim3(256), 0, stream>>>(
        feat, Weff, featqp, featv, W_o, b_o, featvO, WovCat, BpA);
    init_k<<<dim3(N_), dim3(256), 0, stream>>>(obs, emb_obs, loc, Weff, featqp,
        A1f, ecA1b, small5, qp);

    // ---- 30 sequential decode steps, 7 kernels each ----
    for (int s = 0; s < HOR_; s++) {
        attn2_k<<<dim3(N_), dim3(256), 0, stream>>>(qp, emb_obs, emb_gen, fusv,
            W_out, b_out, W_emb, b_emb, loc, Weff, featqp,
            dout, A1f, ecA1b, small5, s);
        // a = [ec|extras] @ WovCat + featvO[b]   (64-row tiles)
        fgemm64_k<9><<<dim3(8, 24), dim3(256), 0, stream>>>(ecA1b, 288, BpA,
            aF, nullptr, 512, nullptr, featvO, 512, 0);
        ln1_k<<<dim3(N_), dim3(256), 0, stream>>>(aF, A1f, feat, ln1_g, ln1_b, h1f, h1b);
        // f1 = relu(h1 @ W_ff1 + b_ff1)  (64-row tiles)
        fgemm64r_k<16><<<dim3(32, 24), dim3(256), 0, stream>>>(h1b, 512, BpF1,
            f1b, 2048, b_ff1);
        // ff = f1 @ W_ff2 + b_ff2  (64-row tiles: B traffic halved)
        fgemm64_k<64><<<dim3(8, 24), dim3(256), 0, stream>>>(f1b, 2048, BpF2,
            ffB, nullptr, 512, b_ff2, nullptr, 0, 0);
        ln2_k<<<dim3(N_), dim3(256), 0, stream>>>(h1f, ffB, ln2_g, ln2_b, small5, h2p);
        // fusv = h2p @ W_fus[0:519] + feat_fus[b]  (64-row tiles)
        fgemm64_k<17><<<dim3(7, 24), dim3(256), 0, stream>>>(h2p, 544, BpFus,
            fusv, nullptr, 448, nullptr, feat_fus, 448, 0);
    }
    // trailing finish for step 29
    finish_k<<<dim3(N_), dim3(256), 0, stream>>>(fusv, W_out, b_out, W_emb, b_emb,
        loc, Weff, featqp, dout, emb_gen, A1f, ecA1b, small5, qp, 29);
}

// Round 13
// 2499.775 us; speedup vs baseline: 1.1050x; 1.1050x over previous
//
#include <hip/hip_runtime.h>
#include <math.h>

#define B_   256
#define N_   1536
#define OBS_ 20
#define HOR_ 30

typedef __bf16 bf16;
typedef bf16  bf16x8 __attribute__((ext_vector_type(8)));
typedef float f32x4  __attribute__((ext_vector_type(4)));

// ---------------------------------------------------------------------------
// Device fp32 GEMM, 32x64 tile, 256 threads, register-prefetch double buffer.
// ---------------------------------------------------------------------------
__device__ __forceinline__ void dev_gemm(
    const float* __restrict__ A, int lda,
    const float* __restrict__ Bw, int ldb,
    float* __restrict__ C, bf16* __restrict__ Cb, int ldc,
    int K, const float* __restrict__ colBias,
    int by, int bx, float* smem)
{
    float (*As)[36] = (float(*)[36])smem;
    float (*Bs)[68] = (float(*)[68])(smem + 16 * 36);
    const int tid = threadIdx.x;
    const int n0 = by * 32, j0 = bx * 64;
    const int a_k = tid & 15, a_r = tid >> 4;
    const int b_j = tid & 63, b_k = tid >> 6;
    const int tx = tid & 15, ty = tid >> 4;
    float acc[2][4] = {};
    float pa0 = A[(size_t)(n0 + a_r) * lda + a_k];
    float pa1 = A[(size_t)(n0 + a_r + 16) * lda + a_k];
    float pb[4];
#pragma unroll
    for (int i = 0; i < 4; i++) pb[i] = Bw[(size_t)(b_k + 4 * i) * ldb + j0 + b_j];
    for (int k0 = 0; k0 < K; k0 += 16) {
        As[a_k][a_r] = pa0;
        As[a_k][a_r + 16] = pa1;
#pragma unroll
        for (int i = 0; i < 4; i++) Bs[b_k + 4 * i][b_j] = pb[i];
        __syncthreads();
        if (k0 + 16 < K) {
            pa0 = A[(size_t)(n0 + a_r) * lda + k0 + 16 + a_k];
            pa1 = A[(size_t)(n0 + a_r + 16) * lda + k0 + 16 + a_k];
#pragma unroll
            for (int i = 0; i < 4; i++)
                pb[i] = Bw[(size_t)(k0 + 16 + b_k + 4 * i) * ldb + j0 + b_j];
        }
#pragma unroll
        for (int kk = 0; kk < 16; kk++) {
            float a0 = As[kk][ty * 2];
            float a1 = As[kk][ty * 2 + 1];
            float4 bv = *(const float4*)&Bs[kk][tx * 4];
            float bb[4] = {bv.x, bv.y, bv.z, bv.w};
#pragma unroll
            for (int j = 0; j < 4; j++) { acc[0][j] += a0 * bb[j]; acc[1][j] += a1 * bb[j]; }
        }
        __syncthreads();
    }
#pragma unroll
    for (int i = 0; i < 2; i++) {
        int n = n0 + ty * 2 + i;
#pragma unroll
        for (int j = 0; j < 4; j++) {
            int jj = j0 + tx * 4 + j;
            float v = acc[i][j];
            if (colBias) v += colBias[jj];
            if (C)  C[(size_t)n * ldc + jj] = v;
            if (Cb) Cb[(size_t)n * ldc + jj] = (bf16)v;
        }
    }
}

// ---------------------------------------------------------------------------
__device__ __forceinline__ void dev_pack(
    int bi, const float* __restrict__ srcF, const bf16* __restrict__ srcB,
    int srcRows, int KC, int J, int lds, bf16* __restrict__ dst)
{
    int idx = bi * 256 + threadIdx.x;
    int total = (J / 16) * KC * 64;
    if (idx >= total) return;
    int lane = idx & 63;
    int kc = (idx >> 6) % KC;
    int jg = idx / (64 * KC);
    int k0 = kc * 32 + (lane >> 4) * 8;
    int col = jg * 16 + (lane & 15);
    bf16x8 v;
#pragma unroll
    for (int i = 0; i < 8; i++) {
        int r = k0 + i;
        float x = 0.f;
        if (r < srcRows) x = srcF ? srcF[(size_t)r * lds + col] : (float)srcB[(size_t)r * lds + col];
        v[i] = (bf16)x;
    }
    *(bf16x8*)&dst[(size_t)idx * 8] = v;
}

__device__ __forceinline__ void dev_emb_obs(
    int bi, const float* __restrict__ obs, const float* __restrict__ Wemb,
    const float* __restrict__ bemb, float* __restrict__ emb_obs)
{
    int tid = bi * 256 + threadIdx.x;
    if (tid >= OBS_ * B_ * 32) return;
    int r = tid >> 5, e = tid & 31;
    float v = obs[r * 2] * Wemb[e] + obs[r * 2 + 1] * Wemb[32 + e] + bemb[e];
    emb_obs[tid] = fmaxf(v, 0.f);
}

// weff: float4 inner loop (4x fewer L2 requests; d-ascending inside the
// vector keeps the fp32 accumulation chain bit-identical).
__device__ __forceinline__ void dev_weff(
    int r, const float* __restrict__ Wqkv, const float* __restrict__ bqkv,
    float* __restrict__ Weff, float* smem)
{
    float* qrow = smem;
    const int t = threadIdx.x;
    for (int j = t; j < 512; j += 256)
        qrow[j] = (r < 512) ? Wqkv[(size_t)r * 1536 + j] : bqkv[j];
    __syncthreads();
    const int h = t >> 5, c = t & 31;
    const float* kp = &Wqkv[(size_t)c * 1536 + 512 + h * 64];
    const float* qp = &qrow[h * 64];
    float acc = 0.f;
#pragma unroll
    for (int d4 = 0; d4 < 16; d4++) {
        float4 kv = *(const float4*)&kp[d4 * 4];
        float4 qv = *(const float4*)&qp[d4 * 4];
        acc += qv.x * kv.x; acc += qv.y * kv.y;
        acc += qv.z * kv.z; acc += qv.w * kv.w;
    }
    Weff[(size_t)r * 256 + t] = acc;
}

__device__ __forceinline__ void dev_wov(
    int row, const float* __restrict__ Wqkv, const float* __restrict__ Wo,
    bf16* __restrict__ WovCat, float* smem)
{
    float* vrow = smem;
    const int h = row >> 5, c = row & 31;
    const int t = threadIdx.x;
    if (t < 64) vrow[t] = Wqkv[(size_t)c * 1536 + 1024 + h * 64 + t];
    __syncthreads();
    for (int j = t; j < 512; j += 256) {
        float acc = 0.f;
#pragma unroll 8
        for (int d = 0; d < 64; d++)
            acc += vrow[d] * Wo[(size_t)(h * 64 + d) * 512 + j];
        WovCat[(size_t)row * 512 + j] = (bf16)acc;
    }
}

// ---------------------------------------------------------------------------
// Prologue phase 1: all independent work, one launch, 2688 blocks.
// ---------------------------------------------------------------------------
__global__ __launch_bounds__(256) void prologue1_k(
    const float* __restrict__ obs, const float* __restrict__ Wemb,
    const float* __restrict__ bemb, float* __restrict__ emb_obs,
    const float* __restrict__ Wqkv, const float* __restrict__ bqkv,
    float* __restrict__ Weff,
    const float* __restrict__ Wo, bf16* __restrict__ WovCat,
    const float* __restrict__ feat, float* __restrict__ featv,
    const float* __restrict__ Wfus, const float* __restrict__ bfus,
    float* __restrict__ feat_fus,
    const float* __restrict__ Wff1, bf16* __restrict__ BpF1,
    const float* __restrict__ Wff2, bf16* __restrict__ BpF2,
    bf16* __restrict__ BpFus)
{
    __shared__ __attribute__((aligned(16))) float smem[16 * 36 + 16 * 68];
    const int b = blockIdx.x;
    if (b < 640) {
        dev_emb_obs(b, obs, Wemb, bemb, emb_obs);
    } else if (b < 1153) {
        dev_weff(b - 640, Wqkv, bqkv, Weff, smem);
    } else if (b < 1409) {
        dev_wov(b - 1153, Wqkv, Wo, WovCat, smem);
    } else if (b < 1473) {            // featv = feat @ Wv + b_qkv[1024:]
        int i = b - 1409;
        dev_gemm(feat, 448, Wqkv + 64 * 1536 + 1024, 1536,
                 featv, nullptr, 512, 448, bqkv + 1024, i >> 3, i & 7, smem);
    } else if (b < 1489) {            // WovCat rows 256..319
        int i = b - 1473;
        dev_gemm(Wqkv + 32 * 1536 + 1024, 1536, Wo, 512,
                 nullptr, WovCat + 256 * 512, 512, 512, nullptr, i >> 3, i & 7, smem);
    } else if (b < 1545) {            // feat_fus = feat @ W_fus[519:] + b_fus
        int i = b - 1489;
        dev_gemm(feat, 448, Wfus + 519 * 448, 448,
                 feat_fus, nullptr, 448, 448, bfus, i / 7, i % 7, smem);
    } else if (b < 2057) {
        dev_pack(b - 1545, Wff1, nullptr, 512, 16, 2048, 2048, BpF1);
    } else if (b < 2569) {
        dev_pack(b - 2057, Wff2, nullptr, 2048, 64, 512, 512, BpF2);
    } else {
        dev_pack(b - 2569, Wfus, nullptr, 519, 17, 448, 448, BpFus);
    }
}

// ---------------------------------------------------------------------------
// Prologue phase 2: depends on phase 1. 168 blocks.
// ---------------------------------------------------------------------------
__global__ __launch_bounds__(256) void prologue2_k(
    const float* __restrict__ feat, const float* __restrict__ Weff,
    float* __restrict__ featqp,
    const float* __restrict__ featv, const float* __restrict__ Wo,
    const float* __restrict__ b_o, float* __restrict__ featvO,
    const bf16* __restrict__ WovCat, bf16* __restrict__ BpA)
{
    __shared__ __attribute__((aligned(16))) float smem[16 * 36 + 16 * 68];
    const int b = blockIdx.x;
    if (b < 32) {                     // featqp = feat @ Weff[64:] + Weff[512]
        int i = b;
        dev_gemm(feat, 448, Weff + 64 * 256, 256,
                 featqp, nullptr, 256, 448, Weff + 512 * 256, i >> 2, i & 3, smem);
    } else if (b < 96) {              // featvO = featv @ W_o + b_o
        int i = b - 32;
        dev_gemm(featv, 512, Wo, 512,
                 featvO, nullptr, 512, 512, b_o, i >> 3, i & 7, smem);
    } else {
        dev_pack(b - 96, nullptr, WovCat, 288, 9, 512, 512, BpA);
    }
}

// ---------------------------------------------------------------------------
// Fast MFMA GEMM, no LDS, prepacked B. Tile 32 rows x 64 cols; block = 256.
// ---------------------------------------------------------------------------
template<int KC>
__global__ __launch_bounds__(256) void fgemm_k(
    const bf16* __restrict__ A, int lda,
    const bf16* __restrict__ Bp,
    float* __restrict__ C, bf16* __restrict__ Cb, int ldc,
    const float* __restrict__ colBias,
    const float* __restrict__ rowMat, int ldRm,
    int doRelu)
{
    const int n0 = blockIdx.y * 32;
    const int j0g = blockIdx.x * 4;
    const int tid = threadIdx.x;
    const int w = tid >> 6, lane = tid & 63;
    const int quad = lane >> 4, m15 = lane & 15;
    const int r0 = (w & 1) * 16;
    const int cg = (w >> 1) * 2;
    const bf16* Arow = &A[(size_t)(n0 + r0 + m15) * lda + quad * 8];
    const bf16* B0 = &Bp[((size_t)(j0g + cg) * KC * 64 + lane) * 8];
    const bf16* B1 = &Bp[((size_t)(j0g + cg + 1) * KC * 64 + lane) * 8];
    f32x4 acc0 = {}, acc1 = {};
#pragma unroll 8
    for (int kc = 0; kc < KC; kc++) {
        bf16x8 af = *(const bf16x8*)&Arow[kc * 32];
        bf16x8 b0 = *(const bf16x8*)&B0[(size_t)kc * 512];
        bf16x8 b1 = *(const bf16x8*)&B1[(size_t)kc * 512];
        acc0 = __builtin_amdgcn_mfma_f32_16x16x32_bf16(af, b0, acc0, 0, 0, 0);
        acc1 = __builtin_amdgcn_mfma_f32_16x16x32_bf16(af, b1, acc1, 0, 0, 0);
    }
#pragma unroll
    for (int g = 0; g < 2; g++) {
        f32x4 a = g ? acc1 : acc0;
        int j = (j0g + cg + g) * 16 + m15;
        float cb = colBias ? colBias[j] : 0.f;
#pragma unroll
        for (int r = 0; r < 4; r++) {
            int n = n0 + r0 + quad * 4 + r;
            float v = a[r] + cb;
            if (rowMat) v += rowMat[(size_t)(n / 6) * ldRm + j];
            if (doRelu) v = fmaxf(v, 0.f);
            if (C)  C[(size_t)n * ldc + j] = v;
            if (Cb) Cb[(size_t)n * ldc + j] = (bf16)v;
        }
    }
}

// ---------------------------------------------------------------------------
// 64-row MFMA GEMM (FF1 specialization: bf16 out + relu + colBias).
// B-fragments loaded once per 2 row-tiles; grid stays wide (768 blocks).
// ---------------------------------------------------------------------------
template<int KC>
__global__ __launch_bounds__(256) void fgemm64r_k(
    const bf16* __restrict__ A, int lda,
    const bf16* __restrict__ Bp,
    bf16* __restrict__ Cb, int ldc,
    const float* __restrict__ colBias)
{
    const int n0 = blockIdx.y * 64;
    const int j0g = blockIdx.x * 4;
    const int tid = threadIdx.x;
    const int w = tid >> 6, lane = tid & 63;
    const int quad = lane >> 4, m15 = lane & 15;
    const int r0 = (w & 1) * 16;
    const int cg = (w >> 1) * 2;
    const bf16* Ar0 = &A[(size_t)(n0 + r0 + m15) * lda + quad * 8];
    const bf16* Ar1 = &A[(size_t)(n0 + 32 + r0 + m15) * lda + quad * 8];
    const bf16* B0 = &Bp[((size_t)(j0g + cg) * KC * 64 + lane) * 8];
    const bf16* B1 = &Bp[((size_t)(j0g + cg + 1) * KC * 64 + lane) * 8];
    f32x4 acc00 = {}, acc01 = {}, acc10 = {}, acc11 = {};
#pragma unroll 8
    for (int kc = 0; kc < KC; kc++) {
        bf16x8 a0 = *(const bf16x8*)&Ar0[kc * 32];
        bf16x8 a1 = *(const bf16x8*)&Ar1[kc * 32];
        bf16x8 b0 = *(const bf16x8*)&B0[(size_t)kc * 512];
        bf16x8 b1 = *(const bf16x8*)&B1[(size_t)kc * 512];
        acc00 = __builtin_amdgcn_mfma_f32_16x16x32_bf16(a0, b0, acc00, 0, 0, 0);
        acc01 = __builtin_amdgcn_mfma_f32_16x16x32_bf16(a0, b1, acc01, 0, 0, 0);
        acc10 = __builtin_amdgcn_mfma_f32_16x16x32_bf16(a1, b0, acc10, 0, 0, 0);
        acc11 = __builtin_amdgcn_mfma_f32_16x16x32_bf16(a1, b1, acc11, 0, 0, 0);
    }
#pragma unroll
    for (int rt = 0; rt < 2; rt++) {
#pragma unroll
        for (int g = 0; g < 2; g++) {
            f32x4 a = rt ? (g ? acc11 : acc10) : (g ? acc01 : acc00);
            int j = (j0g + cg + g) * 16 + m15;
            float cb = colBias[j];
#pragma unroll
            for (int r = 0; r < 4; r++) {
                int n = n0 + rt * 32 + r0 + quad * 4 + r;
                float v = fmaxf(a[r] + cb, 0.f);
                Cb[(size_t)n * ldc + j] = (bf16)v;
            }
        }
    }
}

// ---------------------------------------------------------------------------
// MERGED attn2: finish-work of step s-1 (out, dout, next-state, qp in LDS)
// then attention for step s. grid N x 256. At s==0, qp comes from init_k.
// ---------------------------------------------------------------------------
__global__ __launch_bounds__(256) void attn2_k(
    const float* __restrict__ qp_g,      // init qp (used when s==0)
    const float* __restrict__ emb_obs,
    float* __restrict__ emb_gen,
    const float* __restrict__ fusv,
    const float* __restrict__ Wout, const float* __restrict__ bout,
    const float* __restrict__ Wemb, const float* __restrict__ bemb,
    const float* __restrict__ loc,
    const float* __restrict__ Weff, const float* __restrict__ featqp,
    float* __restrict__ dout,
    float* __restrict__ A1f, bf16* __restrict__ ecA1b,
    float* __restrict__ small5, int s)
{
    __shared__ float qp_s[256];
    __shared__ float emb_s[50 * 33];
    __shared__ float at8[8][64];
    __shared__ float red[8];
    __shared__ float osh[2];
    __shared__ float A1s[64];
    const int n = blockIdx.x, b = n / 6, m = n % 6, tid = threadIdx.x;
    const int tlen = OBS_ + s;

    if (s == 0) {
        qp_s[tid] = qp_g[(size_t)n * 256 + tid];
    } else {
        // ---- finish-work of step s-1 (identical reduction order) ----
        float f0 = fusv[(size_t)n * 448 + tid];
        float p0 = f0 * Wout[tid * 2];
        float p1 = f0 * Wout[tid * 2 + 1];
        if (tid < 192) {
            float f1 = fusv[(size_t)n * 448 + 256 + tid];
            p0 += f1 * Wout[(256 + tid) * 2];
            p1 += f1 * Wout[(256 + tid) * 2 + 1];
        }
#pragma unroll
        for (int o = 32; o > 0; o >>= 1) { p0 += __shfl_xor(p0, o, 64); p1 += __shfl_xor(p1, o, 64); }
        int w = tid >> 6, lane = tid & 63;
        if (lane == 0) { red[w] = p0; red[4 + w] = p1; }
        __syncthreads();
        if (tid == 0) {
            float o0 = red[0] + red[1] + red[2] + red[3] + bout[0];
            float o1 = red[4] + red[5] + red[6] + red[7] + bout[1];
            osh[0] = o0; osh[1] = o1;
            dout[(size_t)b * 360 + m * 60 + (s - 1) * 2]     = o0;
            dout[(size_t)b * 360 + m * 60 + (s - 1) * 2 + 1] = o1;
        }
        __syncthreads();
        float o0 = osh[0], o1 = osh[1];
        float g0 = loc[b * 12 + m * 2], g1 = loc[b * 12 + m * 2 + 1];
        float d0 = g0 - o0, d1 = g1 - o1;
        float tc = (float)(OBS_ + s);    // (s-1)+1 frame index
        if (tid < 32) {
            float e = fmaxf(o0 * Wemb[tid] + o1 * Wemb[32 + tid] + bemb[tid], 0.f);
            emb_gen[((size_t)(s - 1) * N_ + n) * 32 + tid] = e;
            A1s[tid] = e;
        } else if (tid < 64) {
            int c = tid - 32;
            float v;
            if      (c < 8)  v = (c & 1) ? g1 : g0;
            else if (c < 16) v = (c & 1) ? o1 : o0;
            else if (c < 24) v = (c & 1) ? d1 : d0;
            else             v = tc;
            A1s[tid] = v;
        }
        if (tid < 7) {
            float v2 = (tid==0)?o0:(tid==1)?o1:(tid==2)?g0:(tid==3)?g1:(tid==4)?d0:(tid==5)?d1:tc;
            small5[n * 8 + tid] = v2;
        }
        __syncthreads();
        if (tid < 64) {
            A1f[(size_t)n * 64 + tid] = A1s[tid];
            if (tid >= 32) ecA1b[(size_t)n * 288 + 256 + (tid - 32)] = (bf16)A1s[tid];
        }
        float acc = featqp[(size_t)b * 256 + tid];
#pragma unroll 8
        for (int k = 0; k < 64; k++) acc += A1s[k] * Weff[k * 256 + tid];
        qp_s[tid] = acc;
    }

    // ---- stage emb history; newest generated row comes from A1s ----
    for (int idx = tid; idx < tlen * 32; idx += 256) {
        int l = idx >> 5, c = idx & 31;
        float v;
        if (l < OBS_)                 v = emb_obs[((size_t)l * B_ + b) * 32 + c];
        else if (l == tlen - 1)       v = A1s[c];     // only reached when s>=1
        else                          v = emb_gen[((size_t)(l - OBS_) * N_ + n) * 32 + c];
        emb_s[l * 33 + c] = v;
    }
    __syncthreads();

    // ---- attention scores + softmax (per-wave, 2 heads each) ----
    const int w = tid >> 6, lane = tid & 63;
#pragma unroll
    for (int hh = 0; hh < 2; hh++) {
        const int h = w * 2 + hh;
        float sc = -1e30f;
        if (lane < tlen) {
            float s_ = 0.f;
#pragma unroll 8
            for (int c = 0; c < 32; c++) s_ += emb_s[lane * 33 + c] * qp_s[h * 32 + c];
            sc = s_ * 0.125f;
        }
        float mx = sc;
#pragma unroll
        for (int o = 32; o > 0; o >>= 1) mx = fmaxf(mx, __shfl_xor(mx, o, 64));
        float e = (lane < tlen) ? __expf(sc - mx) : 0.f;
        float sm = e;
#pragma unroll
        for (int o = 32; o > 0; o >>= 1) sm += __shfl_xor(sm, o, 64);
        at8[h][lane] = e / sm;
    }
    __syncthreads();

    // ---- context: 1 thread per (head, col); l-ascending = bit-identical ----
    {
        const int h = tid >> 5, c = tid & 31;
        float ec = 0.f;
        for (int l = 0; l < tlen; l++) ec += at8[h][l] * emb_s[l * 33 + c];
        ecA1b[(size_t)n * 288 + h * 32 + c] = (bf16)ec;
    }
}

// ---------------------------------------------------------------------------
// LN1: h1 = LN([A1f|feat] + a) -> h1f fp32 + h1b bf16. grid N x 256.
// ---------------------------------------------------------------------------
__global__ __launch_bounds__(256) void ln1_k(
    const float* __restrict__ a, const float* __restrict__ A1f,
    const float* __restrict__ feat, const float* __restrict__ g,
    const float* __restrict__ bt, float* __restrict__ h1f, bf16* __restrict__ h1b)
{
    __shared__ float red[8];
    const int n = blockIdx.x, b = n / 6, tid = threadIdx.x;
    float r[2]; float s = 0.f, sq = 0.f;
#pragma unroll
    for (int i = 0; i < 2; i++) {
        int j = tid + i * 256;
        float x = (j < 64) ? A1f[(size_t)n * 64 + j] : feat[(size_t)b * 448 + (j - 64)];
        float v = a[(size_t)n * 512 + j] + x;
        r[i] = v; s += v; sq += v * v;
    }
#pragma unroll
    for (int o = 32; o > 0; o >>= 1) { s += __shfl_xor(s, o, 64); sq += __shfl_xor(sq, o, 64); }
    int w = tid >> 6, lane = tid & 63;
    if (lane == 0) { red[w] = s; red[4 + w] = sq; }
    __syncthreads();
    s  = red[0] + red[1] + red[2] + red[3];
    sq = red[4] + red[5] + red[6] + red[7];
    float mu = s * (1.f / 512.f);
    float var = sq * (1.f / 512.f) - mu * mu;
    float rs = rsqrtf(var + 1e-5f);
#pragma unroll
    for (int i = 0; i < 2; i++) {
        int j = tid + i * 256;
        float v = (r[i] - mu) * rs * g[j] + bt[j];
        h1f[(size_t)n * 512 + j] = v;
        h1b[(size_t)n * 512 + j] = (bf16)v;
    }
}

// ---------------------------------------------------------------------------
// LN2: h2p = [LN(h1+ff) | small5 | zeros] as bf16, ld 544. grid N x 256.
// ---------------------------------------------------------------------------
__global__ __launch_bounds__(256) void ln2_k(
    const float* __restrict__ h1, const float* __restrict__ ff,
    const float* __restrict__ g, const float* __restrict__ bt,
    const float* __restrict__ small5, bf16* __restrict__ h2p)
{
    __shared__ float red[8];
    const int n = blockIdx.x, tid = threadIdx.x;
    float r[2]; float s = 0.f, sq = 0.f;
#pragma unroll
    for (int i = 0; i < 2; i++) {
        int j = tid + i * 256;
        float v = h1[(size_t)n * 512 + j] + ff[(size_t)n * 512 + j];
        r[i] = v; s += v; sq += v * v;
    }
#pragma unroll
    for (int o = 32; o > 0; o >>= 1) { s += __shfl_xor(s, o, 64); sq += __shfl_xor(sq, o, 64); }
    int w = tid >> 6, lane = tid & 63;
    if (lane == 0) { red[w] = s; red[4 + w] = sq; }
    __syncthreads();
    s  = red[0] + red[1] + red[2] + red[3];
    sq = red[4] + red[5] + red[6] + red[7];
    float mu = s * (1.f / 512.f);
    float var = sq * (1.f / 512.f) - mu * mu;
    float rs = rsqrtf(var + 1e-5f);
#pragma unroll
    for (int i = 0; i < 2; i++) {
        int j = tid + i * 256;
        h2p[(size_t)n * 544 + j] = (bf16)((r[i] - mu) * rs * g[j] + bt[j]);
    }
    if (tid < 7)  h2p[(size_t)n * 544 + 512 + tid] = (bf16)small5[n * 8 + tid];
    if (tid < 25) h2p[(size_t)n * 544 + 519 + tid] = (bf16)0.f;
}

// ---------------------------------------------------------------------------
// Next-state producer (shared logic)
// ---------------------------------------------------------------------------
__device__ __forceinline__ void next_state(
    int n, int b, int t, float o0, float o1, float g0, float g1, float tc,
    const float* Wemb, const float* bemb, const float* Weff, const float* featqp,
    float* emb_dst, float* A1f, bf16* ecA1b, float* small5, float* qp, float* A1s)
{
    float d0 = g0 - o0, d1 = g1 - o1;
    if (t < 32) {
        float e = fmaxf(o0 * Wemb[t] + o1 * Wemb[32 + t] + bemb[t], 0.f);
        if (emb_dst) emb_dst[t] = e;
        A1s[t] = e;
    } else if (t < 64) {
        int c = t - 32;
        float v;
        if      (c < 8)  v = (c & 1) ? g1 : g0;
        else if (c < 16) v = (c & 1) ? o1 : o0;
        else if (c < 24) v = (c & 1) ? d1 : d0;
        else             v = tc;
        A1s[t] = v;
    }
    if (t < 7) {
        float v2 = (t==0)?o0:(t==1)?o1:(t==2)?g0:(t==3)?g1:(t==4)?d0:(t==5)?d1:tc;
        small5[n * 8 + t] = v2;
    }
    __syncthreads();
    if (t < 64) {
        A1f[(size_t)n * 64 + t] = A1s[t];
        if (t >= 32) ecA1b[(size_t)n * 288 + 256 + (t - 32)] = (bf16)A1s[t];
    }
    float acc = featqp[(size_t)b * 256 + t];
#pragma unroll 8
    for (int k = 0; k < 64; k++) acc += A1s[k] * Weff[k * 256 + t];
    qp[(size_t)n * 256 + t] = acc;
}

__global__ __launch_bounds__(256) void init_k(
    const float* __restrict__ obs, const float* __restrict__ emb_obs,
    const float* __restrict__ loc, const float* __restrict__ Weff,
    const float* __restrict__ featqp,
    float* __restrict__ A1f, bf16* __restrict__ ecA1b,
    float* __restrict__ small5, float* __restrict__ qp)
{
    __shared__ float A1s[64];
    const int n = blockIdx.x, b = n / 6, m = n % 6, t = threadIdx.x;
    float o0 = obs[(19 * B_ + b) * 2], o1 = obs[(19 * B_ + b) * 2 + 1];
    float g0 = loc[b * 12 + m * 2], g1 = loc[b * 12 + m * 2 + 1];
    if (t < 32) {
        A1s[t] = emb_obs[((size_t)19 * B_ + b) * 32 + t];
    } else if (t < 64) {
        int c = t - 32; float d0 = g0 - o0, d1 = g1 - o1; float tc = 20.f;
        float v;
        if      (c < 8)  v = (c & 1) ? g1 : g0;
        else if (c < 16) v = (c & 1) ? o1 : o0;
        else if (c < 24) v = (c & 1) ? d1 : d0;
        else             v = tc;
        A1s[t] = v;
    }
    if (t < 7) {
        float d0 = g0 - o0, d1 = g1 - o1; float tc = 20.f;
        float v2 = (t==0)?o0:(t==1)?o1:(t==2)?g0:(t==3)?g1:(t==4)?d0:(t==5)?d1:tc;
        small5[n * 8 + t] = v2;
    }
    __syncthreads();
    if (t < 64) {
        A1f[(size_t)n * 64 + t] = A1s[t];
        if (t >= 32) ecA1b[(size_t)n * 288 + 256 + (t - 32)] = (bf16)A1s[t];
    }
    float acc = featqp[(size_t)b * 256 + t];
#pragma unroll 8
    for (int k = 0; k < 64; k++) acc += A1s[k] * Weff[k * 256 + t];
    qp[(size_t)n * 256 + t] = acc;
}

// ---------------------------------------------------------------------------
// finish: trailing step only (writes dout for s=29).
// ---------------------------------------------------------------------------
__global__ __launch_bounds__(256) void finish_k(
    const float* __restrict__ fusv, const float* __restrict__ Wout,
    const float* __restrict__ bout, const float* __restrict__ Wemb,
    const float* __restrict__ bemb, const float* __restrict__ loc,
    const float* __restrict__ Weff, const float* __restrict__ featqp,
    float* __restrict__ dout, float* __restrict__ emb_gen,
    float* __restrict__ A1f, bf16* __restrict__ ecA1b,
    float* __restrict__ small5, float* __restrict__ qp, int s)
{
    __shared__ float red[8];
    __shared__ float osh[2];
    __shared__ float A1s[64];
    const int n = blockIdx.x, b = n / 6, m = n % 6, t = threadIdx.x;
    float f0 = fusv[(size_t)n * 448 + t];
    float p0 = f0 * Wout[t * 2];
    float p1 = f0 * Wout[t * 2 + 1];
    if (t < 192) {
        float f1 = fusv[(size_t)n * 448 + 256 + t];
        p0 += f1 * Wout[(256 + t) * 2];
        p1 += f1 * Wout[(256 + t) * 2 + 1];
    }
#pragma unroll
    for (int o = 32; o > 0; o >>= 1) { p0 += __shfl_xor(p0, o, 64); p1 += __shfl_xor(p1, o, 64); }
    int w = t >> 6, lane = t & 63;
    if (lane == 0) { red[w] = p0; red[4 + w] = p1; }
    __syncthreads();
    if (t == 0) {
        float o0 = red[0] + red[1] + red[2] + red[3] + bout[0];
        float o1 = red[4] + red[5] + red[6] + red[7] + bout[1];
        osh[0] = o0; osh[1] = o1;
        dout[(size_t)b * 360 + m * 60 + s * 2]     = o0;
        dout[(size_t)b * 360 + m * 60 + s * 2 + 1] = o1;
    }
    __syncthreads();
    float o0 = osh[0], o1 = osh[1];
    float g0 = loc[b * 12 + m * 2], g1 = loc[b * 12 + m * 2 + 1];
    next_state(n, b, t, o0, o1, g0, g1, (float)(OBS_ + s + 1),
               Wemb, bemb, Weff, featqp,
               &emb_gen[((size_t)s * N_ + n) * 32], A1f, ecA1b, small5, qp, A1s);
}

// ---------------------------------------------------------------------------
extern "C" void kernel_launch(void* const* d_in, const int* in_sizes, int n_in,
                              void* d_out_, int out_size, void* d_ws, size_t ws_size,
                              hipStream_t stream) {
    (void)in_sizes; (void)n_in; (void)out_size; (void)ws_size;
    const float* feat  = (const float*)d_in[0];
    const float* loc   = (const float*)d_in[1];
    const float* obs   = (const float*)d_in[2];
    const float* W_emb = (const float*)d_in[3];
    const float* b_emb = (const float*)d_in[4];
    const float* W_qkv = (const float*)d_in[5];
    const float* b_qkv = (const float*)d_in[6];
    const float* W_o   = (const float*)d_in[7];
    const float* b_o   = (const float*)d_in[8];
    const float* W_ff1 = (const float*)d_in[9];
    const float* b_ff1 = (const float*)d_in[10];
    const float* W_ff2 = (const float*)d_in[11];
    const float* b_ff2 = (const float*)d_in[12];
    const float* ln1_g = (const float*)d_in[13];
    const float* ln1_b = (const float*)d_in[14];
    const float* ln2_g = (const float*)d_in[15];
    const float* ln2_b = (const float*)d_in[16];
    const float* W_fus = (const float*)d_in[17];
    const float* b_fus = (const float*)d_in[18];
    const float* W_out = (const float*)d_in[19];
    const float* b_out = (const float*)d_in[20];
    float* dout = (float*)d_out_;

    float* ws = (float*)d_ws;
    float* Weff     = ws; ws += 513 * 256;
    float* featqp   = ws; ws += 256 * 256;
    float* featv    = ws; ws += 256 * 512;
    float* featvO   = ws; ws += 256 * 512;
    float* feat_fus = ws; ws += 256 * 448;
    float* emb_obs  = ws; ws += OBS_ * B_ * 32;
    float* emb_gen  = ws; ws += HOR_ * N_ * 32;
    float* qp       = ws; ws += (size_t)N_ * 256;
    float* A1f      = ws; ws += (size_t)N_ * 64;
    float* small5   = ws; ws += (size_t)N_ * 8;
    float* h1f      = ws; ws += (size_t)N_ * 512;
    float* aF       = ws; ws += (size_t)N_ * 512;
    float* ffB      = ws; ws += (size_t)N_ * 512;
    float* fusv     = ws; ws += (size_t)N_ * 448;
    bf16* WovCat = (bf16*)ws; ws += (320 * 512) / 2;
    bf16* BpA    = (bf16*)ws; ws += (32 * 9 * 512) / 2;     // 512 cols, KC=9
    bf16* BpF1   = (bf16*)ws; ws += (128 * 16 * 512) / 2;   // 2048 cols, KC=16
    bf16* BpF2   = (bf16*)ws; ws += (32 * 64 * 512) / 2;    // 512 cols, KC=64
    bf16* BpFus  = (bf16*)ws; ws += (28 * 17 * 512) / 2;    // 448 cols, KC=17
    bf16* ecA1b  = (bf16*)ws; ws += ((size_t)N_ * 288) / 2;
    bf16* h1b    = (bf16*)ws; ws += ((size_t)N_ * 512) / 2;
    bf16* f1b    = (bf16*)ws; ws += ((size_t)N_ * 2048) / 2;
    bf16* h2p    = (bf16*)ws; ws += ((size_t)N_ * 544) / 2;

    // ---- prologue: 3 launches ----
    prologue1_k<<<dim3(2688), dim3(256), 0, stream>>>(
        obs, W_emb, b_emb, emb_obs, W_qkv, b_qkv, Weff, W_o, WovCat,
        feat, featv, W_fus, b_fus, feat_fus, W_ff1, BpF1, W_ff2, BpF2, BpFus);
    prologue2_k<<<dim3(168), dim3(256), 0, stream>>>(
        feat, Weff, featqp, featv, W_o, b_o, featvO, WovCat, BpA);
    init_k<<<dim3(N_), dim3(256), 0, stream>>>(obs, emb_obs, loc, Weff, featqp,
        A1f, ecA1b, small5, qp);

    // ---- 30 sequential decode steps, 7 kernels each ----
    for (int s = 0; s < HOR_; s++) {
        attn2_k<<<dim3(N_), dim3(256), 0, stream>>>(qp, emb_obs, emb_gen, fusv,
            W_out, b_out, W_emb, b_emb, loc, Weff, featqp,
            dout, A1f, ecA1b, small5, s);
        // a = [ec|extras] @ WovCat + featvO[b]   (32-row, 384 blocks: wide)
        fgemm_k<9><<<dim3(8, 48), dim3(256), 0, stream>>>(ecA1b, 288, BpA,
            aF, nullptr, 512, nullptr, featvO, 512, 0);
        ln1_k<<<dim3(N_), dim3(256), 0, stream>>>(aF, A1f, feat, ln1_g, ln1_b, h1f, h1b);
        // f1 = relu(h1 @ W_ff1 + b_ff1)  (64-row tiles, 768 blocks: B halved)
        fgemm64r_k<16><<<dim3(32, 24), dim3(256), 0, stream>>>(h1b, 512, BpF1,
            f1b, 2048, b_ff1);
        // ff = f1 @ W_ff2 + b_ff2  (32-row, 384 blocks)
        fgemm_k<64><<<dim3(8, 48), dim3(256), 0, stream>>>(f1b, 2048, BpF2,
            ffB, nullptr, 512, b_ff2, nullptr, 0, 0);
        ln2_k<<<dim3(N_), dim3(256), 0, stream>>>(h1f, ffB, ln2_g, ln2_b, small5, h2p);
        // fusv = h2p @ W_fus[0:519] + feat_fus[b]  (32-row, 336 blocks)
        fgemm_k<17><<<dim3(7, 48), dim3(256), 0, stream>>>(h2p, 544, BpFus,
            fusv, nullptr, 448, nullptr, feat_fus, 448, 0);
    }
    // trailing finish for step 29
    finish_k<<<dim3(N_), dim3(256), 0, stream>>>(fusv, W_out, b_out, W_emb, b_emb,
        loc, Weff, featqp, dout, emb_gen, A1f, ecA1b, small5, qp, 29);
}